// Round 14
// baseline (299.228 us; speedup 1.0000x reference)
//
#include <hip/hip_runtime.h>

// B=8, N=4096, Din=128, Dout=256. TT=16 tokens/block -> M = 3*16 = 48 rows.
// bf16 2-way split (hi/mid) + 3 product-class MFMAs = ~24-bit GEMMs.
// R13: R12's interleaved G1/G2 regressed 122.5->146 from SCRATCH SPILLS:
// [4][2] weight preload arrays = 128 VGPRs of weights + 48 accs > 128-reg cap
// (FETCH +30MB, WRITE +70MB = spill traffic; bank conflicts DID halve as
// predicted). Single-variable fix: weight buffers depth 4 -> 2, explicit
// slot rotation (all indices compile-time). Peak weight liveness 128 -> 64
// VGPRs; live set ~= 48 acc + 64 wt + ~15 tmp ~= 127 <= cap. Everything else
// bit-identical to R12, so R12->R13 isolates spills, R10->R13 isolates the
// interleave value (shared aT reads: LDS 48->24/wave; 2 indep MFMA chains).
#define TT 16
#define NBLK 2048
#define LDA 136   // aT row stride (bf16): 128 + 8 pad

typedef short s16x8 __attribute__((ext_vector_type(8)));
typedef float f32x4 __attribute__((ext_vector_type(4)));

#define SCHED_FENCE() __builtin_amdgcn_sched_barrier(0)

__device__ __forceinline__ unsigned short f2bf(float f) {
  union { float f; unsigned u; } v; v.f = f;
  unsigned r = v.u + 0x7FFFu + ((v.u >> 16) & 1u);   // RNE; inputs finite
  return (unsigned short)(r >> 16);
}
__device__ __forceinline__ float bf2f(unsigned short h) {
  union { unsigned u; float f; } v; v.u = ((unsigned)h) << 16;
  return v.f;
}
__device__ __forceinline__ void split2(float x, unsigned short& h, unsigned short& m) {
  h = f2bf(x);
  m = f2bf(x - bf2f(h));   // exact subtraction
}

// prep1: M3 = A+B+C -> fp32 buffer (for prep2) + bf16x2 planes (for GEMM1)
__global__ __launch_bounds__(256) void prep1_kernel(
    const float* __restrict__ A, const float* __restrict__ Bm,
    const float* __restrict__ C,
    float* __restrict__ M3f,
    unsigned short* __restrict__ M3h, unsigned short* __restrict__ M3m) {
  int tid = blockIdx.x * 256 + threadIdx.x;   // 0..32767
  float s = A[tid] + Bm[tid] + C[tid];
  M3f[tid] = s;
  unsigned short h, m;
  split2(s, h, m);
  M3h[tid] = h; M3m[tid] = m;
}

// prep2: WM3[o][e] = sum_c W[o][c] * M3f[c][e], bf16x2 planes.
// 2-way c-split + LDS combine (deterministic). Passed R12 with absmax 0.5.
__global__ __launch_bounds__(256) void prep2_kernel(
    const float* __restrict__ W, const float* __restrict__ M3f,
    unsigned short* __restrict__ WMh, unsigned short* __restrict__ WMm) {
  __shared__ float wrow[256];
  __shared__ float part[128];
  const int o = blockIdx.x;
  const int t = threadIdx.x;        // 0..255
  const int e = t & 127;
  const int h = t >> 7;             // c-half 0/1
  wrow[t] = W[o * 256 + t];
  __syncthreads();
  float dot = 0.f;
  const int c0 = h * 128;
  #pragma unroll 8
  for (int c = c0; c < c0 + 128; ++c) dot += wrow[c] * M3f[c * 128 + e];
  if (h) part[e] = dot;
  __syncthreads();
  if (!h) {
    float d = dot + part[e];
    unsigned short hh, mm;
    split2(d, hh, mm);
    WMh[o * 128 + e] = hh; WMm[o * 128 + e] = mm;
  }
}

// depth-2 rotating weight buffers: slot is 0/1, all indices compile-time.
#define B1LOADS(slot, ks) { \
  b1h[slot][0] = *(const s16x8*)(M3h + fB + (ks) * 32); \
  b1m[slot][0] = *(const s16x8*)(M3m + fB + (ks) * 32); \
  b1h[slot][1] = *(const s16x8*)(M3h + fB + 2048 + (ks) * 32); \
  b1m[slot][1] = *(const s16x8*)(M3m + fB + 2048 + (ks) * 32); }

#define WMLOADS(slot, ks) { \
  wmh[slot][0] = *(const s16x8*)(WMh + fB + (ks) * 32); \
  wmm[slot][0] = *(const s16x8*)(WMm + fB + (ks) * 32); \
  wmh[slot][1] = *(const s16x8*)(WMh + fB + 2048 + (ks) * 32); \
  wmm[slot][1] = *(const s16x8*)(WMm + fB + 2048 + (ks) * 32); }

// Interleaved G1+G2 step: one aT fragment pair feeds both accumulator chains,
// MFMAs alternating acc1/acc2 (independent -> mutually latency-hiding).
#define GSTEPS(slot, ks) { \
  const int e0 = (ks) * 32 + quad * 8; \
  _Pragma("unroll") \
  for (int mt = 0; mt < 3; ++mt) { \
    s16x8 ah = *(const s16x8*)(aTh + (mt * 16 + nl) * LDA + e0); \
    s16x8 am = *(const s16x8*)(aTm + (mt * 16 + nl) * LDA + e0); \
    _Pragma("unroll") \
    for (int nt = 0; nt < 2; ++nt) { \
      f32x4 a1 = acc1[mt][nt]; \
      f32x4 a2 = acc2[mt][nt]; \
      a1 = __builtin_amdgcn_mfma_f32_16x16x32_bf16(ah, b1h[slot][nt], a1, 0, 0, 0); \
      a2 = __builtin_amdgcn_mfma_f32_16x16x32_bf16(ah, wmh[slot][nt], a2, 0, 0, 0); \
      a1 = __builtin_amdgcn_mfma_f32_16x16x32_bf16(ah, b1m[slot][nt], a1, 0, 0, 0); \
      a2 = __builtin_amdgcn_mfma_f32_16x16x32_bf16(ah, wmm[slot][nt], a2, 0, 0, 0); \
      a1 = __builtin_amdgcn_mfma_f32_16x16x32_bf16(am, b1h[slot][nt], a1, 0, 0, 0); \
      a2 = __builtin_amdgcn_mfma_f32_16x16x32_bf16(am, wmh[slot][nt], a2, 0, 0, 0); \
      acc1[mt][nt] = a1; acc2[mt][nt] = a2; \
    } \
  } }

__global__ __launch_bounds__(512, 4) void affine_vnrelu_mfma(
    const float* __restrict__ X, const float* __restrict__ J,
    const unsigned short* __restrict__ M3h, const unsigned short* __restrict__ M3m,
    const unsigned short* __restrict__ WMh, const unsigned short* __restrict__ WMm,
    float* __restrict__ out) {
  __shared__ unsigned short smem[2 * 48 * LDA];   // aT hi/mid, 26112 B
  unsigned short* aTh = smem;
  unsigned short* aTm = smem + 48 * LDA;

  const int tid = threadIdx.x;
  const int lane = tid & 63;
  const int w = tid >> 6;          // wave 0..7 -> f slice [32w, 32w+32)
  const int quad = lane >> 4;
  const int nl = lane & 15;
  const long g0 = (long)blockIdx.x * TT;
  const int b = (int)(g0 >> 12);   // N = 4096
  const int n0 = (int)(g0 & 4095);
  const int f0 = w * 32;
  const int fB = (f0 + nl) * 128 + quad * 8;
  const f32x4 zz = {0.f, 0.f, 0.f, 0.f};

  // ---- early issue: ks=0 tiles of BOTH weight matrices into slot 0, pinned
  // in flight through phase A (drained by the barrier) -----------------------
  s16x8 b1h[2][2], b1m[2][2];
  s16x8 wmh[2][2], wmm[2][2];
  B1LOADS(0, 0); WMLOADS(0, 0);
  SCHED_FENCE();

  // ---------------- Phase A (vectorized): 1 thread = 4 channels of 1 token --
  {
    int t = tid >> 5;                 // token 0..15
    int dch0 = (tid & 31) * 4;        // channel group
    const float* Xp = X + ((g0 + t) * 128 + dch0) * 3;   // 48B, 16B-aligned
    const float* Jp = J + ((g0 + t) * 128 + dch0) * 6;   // 96B, 16B-aligned
    float xf[12], jf[24];
    #pragma unroll
    for (int q = 0; q < 3; ++q) *(float4*)(xf + 4 * q) = ((const float4*)Xp)[q];
    #pragma unroll
    for (int q = 0; q < 6; ++q) *(float4*)(jf + 4 * q) = ((const float4*)Jp)[q];

    unsigned short hs[3][4], ms[3][4];
    #pragma unroll
    for (int e = 0; e < 4; ++e) {
      float x0 = xf[3 * e], x1 = xf[3 * e + 1], x2 = xf[3 * e + 2];
      float j0 = jf[6 * e],     j1 = jf[6 * e + 1], j2 = jf[6 * e + 2];
      float j3 = jf[6 * e + 3], j4 = jf[6 * e + 4], j5 = jf[6 * e + 5];
      float c00 = j0, c01 = j2, c02 = j4;          // col0 of the 3x2
      float a20 = j1, a21 = j3, a22 = j5;          // col1
      // v_rsq on squared norm; fmaxf(nsq,1e-24) == reference max(n,1e-12)
      float nsq1 = c00 * c00 + c01 * c01 + c02 * c02;
      float inv1 = __builtin_amdgcn_rsqf(fmaxf(nsq1, 1e-24f));
      float b10 = c00 * inv1, b11 = c01 * inv1, b12 = c02 * inv1;
      float pr = b10 * a20 + b11 * a21 + b12 * a22;
      float u0 = a20 - pr * b10, u1 = a21 - pr * b11, u2 = a22 - pr * b12;
      float nsq2 = u0 * u0 + u1 * u1 + u2 * u2;
      float inv2 = __builtin_amdgcn_rsqf(fmaxf(nsq2, 1e-24f));
      float b20 = u0 * inv2, b21 = u1 * inv2, b22 = u2 * inv2;
      float b30 = b11 * b22 - b12 * b21;
      float b31 = b12 * b20 - b10 * b22;
      float b32 = b10 * b21 - b11 * b20;
      split2(b10 * x0 + b11 * x1 + b12 * x2, hs[0][e], ms[0][e]);
      split2(b20 * x0 + b21 * x1 + b22 * x2, hs[1][e], ms[1][e]);
      split2(b30 * x0 + b31 * x1 + b32 * x2, hs[2][e], ms[2][e]);
    }
    #pragma unroll
    for (int i = 0; i < 3; ++i) {
      short4 vh, vm;
      vh.x = hs[i][0]; vh.y = hs[i][1]; vh.z = hs[i][2]; vh.w = hs[i][3];
      vm.x = ms[i][0]; vm.y = ms[i][1]; vm.z = ms[i][2]; vm.w = ms[i][3];
      int ro = (i * 16 + t) * LDA + dch0;
      *(short4*)(aTh + ro) = vh;    // 8B-aligned (LDA even, dch0%4==0)
      *(short4*)(aTm + ro) = vm;
    }
  }
  __syncthreads();   // the single barrier: aT ready

  // ---------------- fused GEMM1+GEMM2 over ks, 2-slot weight rotation -------
  f32x4 acc1[3][2], acc2[3][2];
  #pragma unroll
  for (int mt = 0; mt < 3; ++mt)
    #pragma unroll
    for (int nt = 0; nt < 2; ++nt) { acc1[mt][nt] = zz; acc2[mt][nt] = zz; }

  B1LOADS(1, 1); WMLOADS(1, 1);   // slot1 <- ks1, in flight under GSTEP(0)
  SCHED_FENCE();
  GSTEPS(0, 0);
  B1LOADS(0, 2); WMLOADS(0, 2);   // slot0 <- ks2, in flight under GSTEP(1)
  SCHED_FENCE();
  GSTEPS(1, 1);
  B1LOADS(1, 3); WMLOADS(1, 3);   // slot1 <- ks3, in flight under GSTEP(2)
  SCHED_FENCE();
  GSTEPS(0, 2);
  GSTEPS(1, 3);

  // ---------------- VN-LeakyReLU (lane-local, exact fp32 x) + stores --------
  // lane holds x_i = acc1[i][nt][r], d_i = acc2[i][nt][r] at the SAME (f, t):
  // f = f0 + nt*16 + nl, t = quad*4 + r.
  #pragma unroll
  for (int nt = 0; nt < 2; ++nt) {
    int f = f0 + nt * 16 + nl;
    float* ob = out + ((long)(b * 256 + f) * 3) * 4096 + n0 + quad * 4;
    float o[3][4];
    #pragma unroll
    for (int r = 0; r < 4; ++r) {
      float x0 = acc1[0][nt][r], x1 = acc1[1][nt][r], x2 = acc1[2][nt][r];
      float d0 = acc2[0][nt][r], d1 = acc2[1][nt][r], d2 = acc2[2][nt][r];
      float dot = x0 * d0 + x1 * d1 + x2 * d2;
      float dn = d0 * d0 + d1 * d1 + d2 * d2;
      float s = (dot < 0.0f) ? (0.8f * dot * __builtin_amdgcn_rcpf(dn + 1e-6f))
                             : 0.0f;
      o[0][r] = x0 - s * d0;
      o[1][r] = x1 - s * d1;
      o[2][r] = x2 - s * d2;
    }
    #pragma unroll
    for (int i = 0; i < 3; ++i)
      *(float4*)(ob + ((long)i * 4096)) = make_float4(o[i][0], o[i][1], o[i][2], o[i][3]);
  }
}

extern "C" void kernel_launch(void* const* d_in, const int* in_sizes, int n_in,
                              void* d_out, int out_size, void* d_ws, size_t ws_size,
                              hipStream_t stream) {
  const float* X = (const float*)d_in[0];   // [8,4096,128,3]
  const float* J = (const float*)d_in[1];   // [8,4096,128,3,2]
  const float* A = (const float*)d_in[2];   // [256,128]
  const float* B = (const float*)d_in[3];   // [256,128]
  const float* C = (const float*)d_in[4];   // [256,128]
  const float* W = (const float*)d_in[5];   // [256,256]
  unsigned short* M3h = (unsigned short*)d_ws;          // 32768 u16
  unsigned short* M3m = M3h + 128 * 256;                // 32768 u16
  unsigned short* WMh = M3m + 128 * 256;                // 32768 u16
  unsigned short* WMm = WMh + 128 * 256;                // 32768 u16
  float* M3f = (float*)(WMm + 128 * 256);               // 32768 f32; total 384KB
  float* out = (float*)d_out;               // [8,256,3,4096]

  prep1_kernel<<<128, 256, 0, stream>>>(A, B, C, M3f, M3h, M3m);
  prep2_kernel<<<256, 256, 0, stream>>>(W, M3f, WMh, WMm);
  affine_vnrelu_mfma<<<NBLK, 512, 0, stream>>>(
      X, J, M3h, M3m, WMh, WMm, out);
}

// Round 16
// 280.062 us; speedup vs baseline: 1.0684x; 1.0684x over previous
//
#include <hip/hip_runtime.h>

// B=8, N=4096, Din=128, Dout=256. TT=16 tokens/block -> M = 3*16 = 48 rows.
// bf16 2-way split (hi/mid) + 3 product-class MFMAs = ~24-bit GEMMs.
// R14 (resubmit — container failed twice; kernel never ran):
// R13's depth-2 rotation did NOT remove the spills (FETCH/WRITE/VGPR all
// identical to R12). Corrected accounting: VGPR_Count=64 is ARCH VGPRs only;
// + 48 acc (AGPR side of unified file) + 64 pinned weight regs ~= 130 > the
// (512,4) cap of 128 -> allocator spills ~17 dwords/thread (= the observed
// +70MB write / +30MB fetch) in BOTH R12 and R13. The interleave has never
// run spill-free; its predicted bank-conflict halving IS confirmed (3.1M ->
// 1.57M). Single-variable change: __launch_bounds__(512,4) -> (512,3), cap
// 128 -> 170. Allocator uses ~135 -> no spills. Occupancy may drop to 1
// block/CU (8 waves) — R6/R7 showed this kernel is occupancy-insensitive
// (43->60% occ: zero effect; all pipes <16%). Everything else identical.
#define TT 16
#define NBLK 2048
#define LDA 136   // aT row stride (bf16): 128 + 8 pad

typedef short s16x8 __attribute__((ext_vector_type(8)));
typedef float f32x4 __attribute__((ext_vector_type(4)));

#define SCHED_FENCE() __builtin_amdgcn_sched_barrier(0)

__device__ __forceinline__ unsigned short f2bf(float f) {
  union { float f; unsigned u; } v; v.f = f;
  unsigned r = v.u + 0x7FFFu + ((v.u >> 16) & 1u);   // RNE; inputs finite
  return (unsigned short)(r >> 16);
}
__device__ __forceinline__ float bf2f(unsigned short h) {
  union { unsigned u; float f; } v; v.u = ((unsigned)h) << 16;
  return v.f;
}
__device__ __forceinline__ void split2(float x, unsigned short& h, unsigned short& m) {
  h = f2bf(x);
  m = f2bf(x - bf2f(h));   // exact subtraction
}

// prep1: M3 = A+B+C -> fp32 buffer (for prep2) + bf16x2 planes (for GEMM1)
__global__ __launch_bounds__(256) void prep1_kernel(
    const float* __restrict__ A, const float* __restrict__ Bm,
    const float* __restrict__ C,
    float* __restrict__ M3f,
    unsigned short* __restrict__ M3h, unsigned short* __restrict__ M3m) {
  int tid = blockIdx.x * 256 + threadIdx.x;   // 0..32767
  float s = A[tid] + Bm[tid] + C[tid];
  M3f[tid] = s;
  unsigned short h, m;
  split2(s, h, m);
  M3h[tid] = h; M3m[tid] = m;
}

// prep2: WM3[o][e] = sum_c W[o][c] * M3f[c][e], bf16x2 planes.
// 2-way c-split + LDS combine (deterministic). Passed R12/R13, absmax 0.5.
__global__ __launch_bounds__(256) void prep2_kernel(
    const float* __restrict__ W, const float* __restrict__ M3f,
    unsigned short* __restrict__ WMh, unsigned short* __restrict__ WMm) {
  __shared__ float wrow[256];
  __shared__ float part[128];
  const int o = blockIdx.x;
  const int t = threadIdx.x;        // 0..255
  const int e = t & 127;
  const int h = t >> 7;             // c-half 0/1
  wrow[t] = W[o * 256 + t];
  __syncthreads();
  float dot = 0.f;
  const int c0 = h * 128;
  #pragma unroll 8
  for (int c = c0; c < c0 + 128; ++c) dot += wrow[c] * M3f[c * 128 + e];
  if (h) part[e] = dot;
  __syncthreads();
  if (!h) {
    float d = dot + part[e];
    unsigned short hh, mm;
    split2(d, hh, mm);
    WMh[o * 128 + e] = hh; WMm[o * 128 + e] = mm;
  }
}

// depth-2 rotating weight buffers: slot is 0/1, all indices compile-time.
#define B1LOADS(slot, ks) { \
  b1h[slot][0] = *(const s16x8*)(M3h + fB + (ks) * 32); \
  b1m[slot][0] = *(const s16x8*)(M3m + fB + (ks) * 32); \
  b1h[slot][1] = *(const s16x8*)(M3h + fB + 2048 + (ks) * 32); \
  b1m[slot][1] = *(const s16x8*)(M3m + fB + 2048 + (ks) * 32); }

#define WMLOADS(slot, ks) { \
  wmh[slot][0] = *(const s16x8*)(WMh + fB + (ks) * 32); \
  wmm[slot][0] = *(const s16x8*)(WMm + fB + (ks) * 32); \
  wmh[slot][1] = *(const s16x8*)(WMh + fB + 2048 + (ks) * 32); \
  wmm[slot][1] = *(const s16x8*)(WMm + fB + 2048 + (ks) * 32); }

// Interleaved G1+G2 step: one aT fragment pair feeds both accumulator chains,
// MFMAs alternating acc1/acc2 (independent -> mutually latency-hiding).
#define GSTEPS(slot, ks) { \
  const int e0 = (ks) * 32 + quad * 8; \
  _Pragma("unroll") \
  for (int mt = 0; mt < 3; ++mt) { \
    s16x8 ah = *(const s16x8*)(aTh + (mt * 16 + nl) * LDA + e0); \
    s16x8 am = *(const s16x8*)(aTm + (mt * 16 + nl) * LDA + e0); \
    _Pragma("unroll") \
    for (int nt = 0; nt < 2; ++nt) { \
      f32x4 a1 = acc1[mt][nt]; \
      f32x4 a2 = acc2[mt][nt]; \
      a1 = __builtin_amdgcn_mfma_f32_16x16x32_bf16(ah, b1h[slot][nt], a1, 0, 0, 0); \
      a2 = __builtin_amdgcn_mfma_f32_16x16x32_bf16(ah, wmh[slot][nt], a2, 0, 0, 0); \
      a1 = __builtin_amdgcn_mfma_f32_16x16x32_bf16(ah, b1m[slot][nt], a1, 0, 0, 0); \
      a2 = __builtin_amdgcn_mfma_f32_16x16x32_bf16(ah, wmm[slot][nt], a2, 0, 0, 0); \
      a1 = __builtin_amdgcn_mfma_f32_16x16x32_bf16(am, b1h[slot][nt], a1, 0, 0, 0); \
      a2 = __builtin_amdgcn_mfma_f32_16x16x32_bf16(am, wmh[slot][nt], a2, 0, 0, 0); \
      acc1[mt][nt] = a1; acc2[mt][nt] = a2; \
    } \
  } }

__global__ __launch_bounds__(512, 3) void affine_vnrelu_mfma(
    const float* __restrict__ X, const float* __restrict__ J,
    const unsigned short* __restrict__ M3h, const unsigned short* __restrict__ M3m,
    const unsigned short* __restrict__ WMh, const unsigned short* __restrict__ WMm,
    float* __restrict__ out) {
  __shared__ unsigned short smem[2 * 48 * LDA];   // aT hi/mid, 26112 B
  unsigned short* aTh = smem;
  unsigned short* aTm = smem + 48 * LDA;

  const int tid = threadIdx.x;
  const int lane = tid & 63;
  const int w = tid >> 6;          // wave 0..7 -> f slice [32w, 32w+32)
  const int quad = lane >> 4;
  const int nl = lane & 15;
  const long g0 = (long)blockIdx.x * TT;
  const int b = (int)(g0 >> 12);   // N = 4096
  const int n0 = (int)(g0 & 4095);
  const int f0 = w * 32;
  const int fB = (f0 + nl) * 128 + quad * 8;
  const f32x4 zz = {0.f, 0.f, 0.f, 0.f};

  // ---- early issue: ks=0 tiles of BOTH weight matrices into slot 0, pinned
  // in flight through phase A (drained by the barrier) -----------------------
  s16x8 b1h[2][2], b1m[2][2];
  s16x8 wmh[2][2], wmm[2][2];
  B1LOADS(0, 0); WMLOADS(0, 0);
  SCHED_FENCE();

  // ---------------- Phase A (vectorized): 1 thread = 4 channels of 1 token --
  {
    int t = tid >> 5;                 // token 0..15
    int dch0 = (tid & 31) * 4;        // channel group
    const float* Xp = X + ((g0 + t) * 128 + dch0) * 3;   // 48B, 16B-aligned
    const float* Jp = J + ((g0 + t) * 128 + dch0) * 6;   // 96B, 16B-aligned
    float xf[12], jf[24];
    #pragma unroll
    for (int q = 0; q < 3; ++q) *(float4*)(xf + 4 * q) = ((const float4*)Xp)[q];
    #pragma unroll
    for (int q = 0; q < 6; ++q) *(float4*)(jf + 4 * q) = ((const float4*)Jp)[q];

    unsigned short hs[3][4], ms[3][4];
    #pragma unroll
    for (int e = 0; e < 4; ++e) {
      float x0 = xf[3 * e], x1 = xf[3 * e + 1], x2 = xf[3 * e + 2];
      float j0 = jf[6 * e],     j1 = jf[6 * e + 1], j2 = jf[6 * e + 2];
      float j3 = jf[6 * e + 3], j4 = jf[6 * e + 4], j5 = jf[6 * e + 5];
      float c00 = j0, c01 = j2, c02 = j4;          // col0 of the 3x2
      float a20 = j1, a21 = j3, a22 = j5;          // col1
      // v_rsq on squared norm; fmaxf(nsq,1e-24) == reference max(n,1e-12)
      float nsq1 = c00 * c00 + c01 * c01 + c02 * c02;
      float inv1 = __builtin_amdgcn_rsqf(fmaxf(nsq1, 1e-24f));
      float b10 = c00 * inv1, b11 = c01 * inv1, b12 = c02 * inv1;
      float pr = b10 * a20 + b11 * a21 + b12 * a22;
      float u0 = a20 - pr * b10, u1 = a21 - pr * b11, u2 = a22 - pr * b12;
      float nsq2 = u0 * u0 + u1 * u1 + u2 * u2;
      float inv2 = __builtin_amdgcn_rsqf(fmaxf(nsq2, 1e-24f));
      float b20 = u0 * inv2, b21 = u1 * inv2, b22 = u2 * inv2;
      float b30 = b11 * b22 - b12 * b21;
      float b31 = b12 * b20 - b10 * b22;
      float b32 = b10 * b21 - b11 * b20;
      split2(b10 * x0 + b11 * x1 + b12 * x2, hs[0][e], ms[0][e]);
      split2(b20 * x0 + b21 * x1 + b22 * x2, hs[1][e], ms[1][e]);
      split2(b30 * x0 + b31 * x1 + b32 * x2, hs[2][e], ms[2][e]);
    }
    #pragma unroll
    for (int i = 0; i < 3; ++i) {
      short4 vh, vm;
      vh.x = hs[i][0]; vh.y = hs[i][1]; vh.z = hs[i][2]; vh.w = hs[i][3];
      vm.x = ms[i][0]; vm.y = ms[i][1]; vm.z = ms[i][2]; vm.w = ms[i][3];
      int ro = (i * 16 + t) * LDA + dch0;
      *(short4*)(aTh + ro) = vh;    // 8B-aligned (LDA even, dch0%4==0)
      *(short4*)(aTm + ro) = vm;
    }
  }
  __syncthreads();   // the single barrier: aT ready

  // ---------------- fused GEMM1+GEMM2 over ks, 2-slot weight rotation -------
  f32x4 acc1[3][2], acc2[3][2];
  #pragma unroll
  for (int mt = 0; mt < 3; ++mt)
    #pragma unroll
    for (int nt = 0; nt < 2; ++nt) { acc1[mt][nt] = zz; acc2[mt][nt] = zz; }

  B1LOADS(1, 1); WMLOADS(1, 1);   // slot1 <- ks1, in flight under GSTEP(0)
  SCHED_FENCE();
  GSTEPS(0, 0);
  B1LOADS(0, 2); WMLOADS(0, 2);   // slot0 <- ks2, in flight under GSTEP(1)
  SCHED_FENCE();
  GSTEPS(1, 1);
  B1LOADS(1, 3); WMLOADS(1, 3);   // slot1 <- ks3, in flight under GSTEP(2)
  SCHED_FENCE();
  GSTEPS(0, 2);
  GSTEPS(1, 3);

  // ---------------- VN-LeakyReLU (lane-local, exact fp32 x) + stores --------
  // lane holds x_i = acc1[i][nt][r], d_i = acc2[i][nt][r] at the SAME (f, t):
  // f = f0 + nt*16 + nl, t = quad*4 + r.
  #pragma unroll
  for (int nt = 0; nt < 2; ++nt) {
    int f = f0 + nt * 16 + nl;
    float* ob = out + ((long)(b * 256 + f) * 3) * 4096 + n0 + quad * 4;
    float o[3][4];
    #pragma unroll
    for (int r = 0; r < 4; ++r) {
      float x0 = acc1[0][nt][r], x1 = acc1[1][nt][r], x2 = acc1[2][nt][r];
      float d0 = acc2[0][nt][r], d1 = acc2[1][nt][r], d2 = acc2[2][nt][r];
      float dot = x0 * d0 + x1 * d1 + x2 * d2;
      float dn = d0 * d0 + d1 * d1 + d2 * d2;
      float s = (dot < 0.0f) ? (0.8f * dot * __builtin_amdgcn_rcpf(dn + 1e-6f))
                             : 0.0f;
      o[0][r] = x0 - s * d0;
      o[1][r] = x1 - s * d1;
      o[2][r] = x2 - s * d2;
    }
    #pragma unroll
    for (int i = 0; i < 3; ++i)
      *(float4*)(ob + ((long)i * 4096)) = make_float4(o[i][0], o[i][1], o[i][2], o[i][3]);
  }
}

extern "C" void kernel_launch(void* const* d_in, const int* in_sizes, int n_in,
                              void* d_out, int out_size, void* d_ws, size_t ws_size,
                              hipStream_t stream) {
  const float* X = (const float*)d_in[0];   // [8,4096,128,3]
  const float* J = (const float*)d_in[1];   // [8,4096,128,3,2]
  const float* A = (const float*)d_in[2];   // [256,128]
  const float* B = (const float*)d_in[3];   // [256,128]
  const float* C = (const float*)d_in[4];   // [256,128]
  const float* W = (const float*)d_in[5];   // [256,256]
  unsigned short* M3h = (unsigned short*)d_ws;          // 32768 u16
  unsigned short* M3m = M3h + 128 * 256;                // 32768 u16
  unsigned short* WMh = M3m + 128 * 256;                // 32768 u16
  unsigned short* WMm = WMh + 128 * 256;                // 32768 u16
  float* M3f = (float*)(WMm + 128 * 256);               // 32768 f32; total 384KB
  float* out = (float*)d_out;               // [8,256,3,4096]

  prep1_kernel<<<128, 256, 0, stream>>>(A, B, C, M3f, M3h, M3m);
  prep2_kernel<<<256, 256, 0, stream>>>(W, M3f, WMh, WMm);
  affine_vnrelu_mfma<<<NBLK, 512, 0, stream>>>(
      X, J, M3h, M3m, WMh, WMm, out);
}

// Round 22
// 278.518 us; speedup vs baseline: 1.0744x; 1.0055x over previous
//
#include <hip/hip_runtime.h>

// B=8, N=4096, Din=128, Dout=256. TT=16 tokens/tile -> M = 3*16 = 48 rows.
// bf16 2-way split (hi/mid) + 3 product-class MFMAs = ~24-bit GEMMs.
// R15 (6th submit — five GPUAcquisitionTimeouts; kernel never ran):
// PERSISTENT PIPELINE. R14 closed the interleave question (spill-free
// interleave == R10 separated == ~123us; occupancy 36->23% no effect). R11
// ablation: full ~= t1 + t2 + store -> phases compose SERIALLY. Cause:
// co-resident blocks run in LOCKSTEP (same launch, same barriers) -> no phase
// diversity on a CU, so occupancy never helps. Fix: create the diversity
// INSIDE a persistent block. NBLK 2048 -> 256 (1 block/CU), each block loops
// NTILE=8 tiles:
//   top:    issue X/J loads for tile t+1 (36 regs, pinned)   } ~900cy HBM
//   body:   GEMM(tile t) from LDS, weight-slot rotation      } latency hides
//   epi:    VN + stores(tile t) (fire-and-forget)            } under GEMM
//   bar; next ks0 weight loads; GS-process t+1 -> LDS; bar
// Only ~700cy of GS VALU per turn remains un-overlapped.
// Regs: acc 48 + weights 64 + X/J 36 + temps ~= 210 -> __launch_bounds__(512,2)
// cap 256 (1 block/CU; occupancy-insensitivity proven R6/R7/R14). Spill check:
// FETCH/WRITE must stay ~76K/98K.
#define TT 16
#define NBLK 256
#define NTILE 8    // 256 blocks x 8 tiles = 2048 tiles = 32768 tokens
#define LDA 136    // aT row stride (bf16): 128 + 8 pad

typedef short s16x8 __attribute__((ext_vector_type(8)));
typedef float f32x4 __attribute__((ext_vector_type(4)));

#define SCHED_FENCE() __builtin_amdgcn_sched_barrier(0)

__device__ __forceinline__ unsigned short f2bf(float f) {
  union { float f; unsigned u; } v; v.f = f;
  unsigned r = v.u + 0x7FFFu + ((v.u >> 16) & 1u);   // RNE; inputs finite
  return (unsigned short)(r >> 16);
}
__device__ __forceinline__ float bf2f(unsigned short h) {
  union { unsigned u; float f; } v; v.u = ((unsigned)h) << 16;
  return v.f;
}
__device__ __forceinline__ void split2(float x, unsigned short& h, unsigned short& m) {
  h = f2bf(x);
  m = f2bf(x - bf2f(h));   // exact subtraction
}

// prep1: M3 = A+B+C -> fp32 buffer (for prep2) + bf16x2 planes (for GEMM1)
__global__ __launch_bounds__(256) void prep1_kernel(
    const float* __restrict__ A, const float* __restrict__ Bm,
    const float* __restrict__ C,
    float* __restrict__ M3f,
    unsigned short* __restrict__ M3h, unsigned short* __restrict__ M3m) {
  int tid = blockIdx.x * 256 + threadIdx.x;   // 0..32767
  float s = A[tid] + Bm[tid] + C[tid];
  M3f[tid] = s;
  unsigned short h, m;
  split2(s, h, m);
  M3h[tid] = h; M3m[tid] = m;
}

// prep2: WM3[o][e] = sum_c W[o][c] * M3f[c][e], bf16x2 planes.
// 2-way c-split + LDS combine (deterministic). Passed R12-R14, absmax 0.5.
__global__ __launch_bounds__(256) void prep2_kernel(
    const float* __restrict__ W, const float* __restrict__ M3f,
    unsigned short* __restrict__ WMh, unsigned short* __restrict__ WMm) {
  __shared__ float wrow[256];
  __shared__ float part[128];
  const int o = blockIdx.x;
  const int t = threadIdx.x;        // 0..255
  const int e = t & 127;
  const int h = t >> 7;             // c-half 0/1
  wrow[t] = W[o * 256 + t];
  __syncthreads();
  float dot = 0.f;
  const int c0 = h * 128;
  #pragma unroll 8
  for (int c = c0; c < c0 + 128; ++c) dot += wrow[c] * M3f[c * 128 + e];
  if (h) part[e] = dot;
  __syncthreads();
  if (!h) {
    float d = dot + part[e];
    unsigned short hh, mm;
    split2(d, hh, mm);
    WMh[o * 128 + e] = hh; WMm[o * 128 + e] = mm;
  }
}

// weight-slot loads (slot/ks compile-time; planes [256][128] u16)
#define B1LOADS(slot, ks) { \
  b1h[slot][0] = *(const s16x8*)(M3h + fB + (ks) * 32); \
  b1m[slot][0] = *(const s16x8*)(M3m + fB + (ks) * 32); \
  b1h[slot][1] = *(const s16x8*)(M3h + fB + 2048 + (ks) * 32); \
  b1m[slot][1] = *(const s16x8*)(M3m + fB + 2048 + (ks) * 32); }

#define WMLOADS(slot, ks) { \
  wmh[slot][0] = *(const s16x8*)(WMh + fB + (ks) * 32); \
  wmm[slot][0] = *(const s16x8*)(WMm + fB + (ks) * 32); \
  wmh[slot][1] = *(const s16x8*)(WMh + fB + 2048 + (ks) * 32); \
  wmm[slot][1] = *(const s16x8*)(WMm + fB + 2048 + (ks) * 32); }

// Interleaved dual-GEMM step (R14-validated; acc1/acc2 independent chains)
#define GSTEPS(slot, ks) { \
  const int e0 = (ks) * 32 + quad * 8; \
  _Pragma("unroll") \
  for (int mt = 0; mt < 3; ++mt) { \
    s16x8 ah = *(const s16x8*)(aTh + (mt * 16 + nl) * LDA + e0); \
    s16x8 am = *(const s16x8*)(aTm + (mt * 16 + nl) * LDA + e0); \
    _Pragma("unroll") \
    for (int nt = 0; nt < 2; ++nt) { \
      f32x4 a1 = acc1[mt][nt]; \
      f32x4 a2 = acc2[mt][nt]; \
      a1 = __builtin_amdgcn_mfma_f32_16x16x32_bf16(ah, b1h[slot][nt], a1, 0, 0, 0); \
      a2 = __builtin_amdgcn_mfma_f32_16x16x32_bf16(ah, wmh[slot][nt], a2, 0, 0, 0); \
      a1 = __builtin_amdgcn_mfma_f32_16x16x32_bf16(ah, b1m[slot][nt], a1, 0, 0, 0); \
      a2 = __builtin_amdgcn_mfma_f32_16x16x32_bf16(ah, wmm[slot][nt], a2, 0, 0, 0); \
      a1 = __builtin_amdgcn_mfma_f32_16x16x32_bf16(am, b1h[slot][nt], a1, 0, 0, 0); \
      a2 = __builtin_amdgcn_mfma_f32_16x16x32_bf16(am, wmh[slot][nt], a2, 0, 0, 0); \
      acc1[mt][nt] = a1; acc2[mt][nt] = a2; \
    } \
  } }

// issue X/J loads for tile with token base g0t into xf[12]/jf[24]
#define LOADXJ(g0t) { \
  const float* Xp = X + (((g0t) + tA) * 128 + dch0) * 3; \
  const float* Jp = J + (((g0t) + tA) * 128 + dch0) * 6; \
  _Pragma("unroll") \
  for (int q = 0; q < 3; ++q) *(float4*)(xf + 4 * q) = ((const float4*)Xp)[q]; \
  _Pragma("unroll") \
  for (int q = 0; q < 6; ++q) *(float4*)(jf + 4 * q) = ((const float4*)Jp)[q]; }

// Gram-Schmidt + a = R^T X on xf/jf, split to bf16x2, write aT LDS
#define GSPROC() { \
  unsigned short hs[3][4], ms[3][4]; \
  _Pragma("unroll") \
  for (int e = 0; e < 4; ++e) { \
    float x0 = xf[3 * e], x1 = xf[3 * e + 1], x2 = xf[3 * e + 2]; \
    float j0 = jf[6 * e],     j1 = jf[6 * e + 1], j2 = jf[6 * e + 2]; \
    float j3 = jf[6 * e + 3], j4 = jf[6 * e + 4], j5 = jf[6 * e + 5]; \
    float c00 = j0, c01 = j2, c02 = j4; \
    float a20 = j1, a21 = j3, a22 = j5; \
    float nsq1 = c00 * c00 + c01 * c01 + c02 * c02; \
    float inv1 = __builtin_amdgcn_rsqf(fmaxf(nsq1, 1e-24f)); \
    float b10 = c00 * inv1, b11 = c01 * inv1, b12 = c02 * inv1; \
    float pr = b10 * a20 + b11 * a21 + b12 * a22; \
    float u0 = a20 - pr * b10, u1 = a21 - pr * b11, u2 = a22 - pr * b12; \
    float nsq2 = u0 * u0 + u1 * u1 + u2 * u2; \
    float inv2 = __builtin_amdgcn_rsqf(fmaxf(nsq2, 1e-24f)); \
    float b20 = u0 * inv2, b21 = u1 * inv2, b22 = u2 * inv2; \
    float b30 = b11 * b22 - b12 * b21; \
    float b31 = b12 * b20 - b10 * b22; \
    float b32 = b10 * b21 - b11 * b20; \
    split2(b10 * x0 + b11 * x1 + b12 * x2, hs[0][e], ms[0][e]); \
    split2(b20 * x0 + b21 * x1 + b22 * x2, hs[1][e], ms[1][e]); \
    split2(b30 * x0 + b31 * x1 + b32 * x2, hs[2][e], ms[2][e]); \
  } \
  _Pragma("unroll") \
  for (int i = 0; i < 3; ++i) { \
    short4 vh, vm; \
    vh.x = hs[i][0]; vh.y = hs[i][1]; vh.z = hs[i][2]; vh.w = hs[i][3]; \
    vm.x = ms[i][0]; vm.y = ms[i][1]; vm.z = ms[i][2]; vm.w = ms[i][3]; \
    int ro = (i * 16 + tA) * LDA + dch0; \
    *(short4*)(aTh + ro) = vh; \
    *(short4*)(aTm + ro) = vm; \
  } }

__global__ __launch_bounds__(512, 2) void affine_vnrelu_mfma(
    const float* __restrict__ X, const float* __restrict__ J,
    const unsigned short* __restrict__ M3h, const unsigned short* __restrict__ M3m,
    const unsigned short* __restrict__ WMh, const unsigned short* __restrict__ WMm,
    float* __restrict__ out) {
  __shared__ unsigned short smem[2 * 48 * LDA];   // aT hi/mid, 26112 B
  unsigned short* aTh = smem;
  unsigned short* aTm = smem + 48 * LDA;

  const int tid = threadIdx.x;
  const int lane = tid & 63;
  const int w = tid >> 6;          // wave 0..7 -> f slice [32w, 32w+32)
  const int quad = lane >> 4;
  const int nl = lane & 15;
  const int f0 = w * 32;
  const int fB = (f0 + nl) * 128 + quad * 8;
  const int tA = tid >> 5;          // phase-A token 0..15
  const int dch0 = (tid & 31) * 4;  // phase-A channel group
  const f32x4 zz = {0.f, 0.f, 0.f, 0.f};

  s16x8 b1h[2][2], b1m[2][2];
  s16x8 wmh[2][2], wmm[2][2];
  float xf[12], jf[24];

  const long gbase = (long)blockIdx.x * NTILE * TT;

  // ---------------- prologue: tile 0 X/J + ks0 weights + GS -----------------
  LOADXJ(gbase);
  B1LOADS(0, 0); WMLOADS(0, 0);
  SCHED_FENCE();
  GSPROC();
  __syncthreads();   // aT(0) ready

  for (int it = 0; it < NTILE; ++it) {
    const long g0c = gbase + (long)it * TT;

    // ---- issue next tile's X/J loads: HBM latency hides under this GEMM ----
    if (it + 1 < NTILE) { LOADXJ(g0c + TT); }
    SCHED_FENCE();

    // ---- fused dual-GEMM over ks, 2-slot weight rotation (R14 structure) ---
    f32x4 acc1[3][2], acc2[3][2];
    #pragma unroll
    for (int mt = 0; mt < 3; ++mt)
      #pragma unroll
      for (int nt = 0; nt < 2; ++nt) { acc1[mt][nt] = zz; acc2[mt][nt] = zz; }

    B1LOADS(1, 1); WMLOADS(1, 1);
    SCHED_FENCE();
    GSTEPS(0, 0);
    B1LOADS(0, 2); WMLOADS(0, 2);
    SCHED_FENCE();
    GSTEPS(1, 1);
    B1LOADS(1, 3); WMLOADS(1, 3);
    SCHED_FENCE();
    GSTEPS(0, 2);
    GSTEPS(1, 3);

    // ---- VN-LeakyReLU + stores for tile it (fire-and-forget) ---------------
    {
      const int bb = (int)(g0c >> 12);
      const int n0 = (int)(g0c & 4095);
      #pragma unroll
      for (int nt = 0; nt < 2; ++nt) {
        int f = f0 + nt * 16 + nl;
        float* ob = out + ((long)(bb * 256 + f) * 3) * 4096 + n0 + quad * 4;
        float o[3][4];
        #pragma unroll
        for (int r = 0; r < 4; ++r) {
          float x0 = acc1[0][nt][r], x1 = acc1[1][nt][r], x2 = acc1[2][nt][r];
          float d0 = acc2[0][nt][r], d1 = acc2[1][nt][r], d2 = acc2[2][nt][r];
          float dot = x0 * d0 + x1 * d1 + x2 * d2;
          float dn = d0 * d0 + d1 * d1 + d2 * d2;
          float s = (dot < 0.0f) ? (0.8f * dot * __builtin_amdgcn_rcpf(dn + 1e-6f))
                                 : 0.0f;
          o[0][r] = x0 - s * d0;
          o[1][r] = x1 - s * d1;
          o[2][r] = x2 - s * d2;
        }
        #pragma unroll
        for (int i = 0; i < 3; ++i)
          *(float4*)(ob + ((long)i * 4096)) = make_float4(o[i][0], o[i][1], o[i][2], o[i][3]);
      }
    }

    // ---- GS-process tile it+1 into LDS (stores of it drain underneath) -----
    if (it + 1 < NTILE) {
      __syncthreads();                 // all waves done reading aT(it)
      B1LOADS(0, 0); WMLOADS(0, 0);    // next iter's ks0 weights, hide under GS
      SCHED_FENCE();
      GSPROC();
      __syncthreads();                 // aT(it+1) ready
    }
  }
}

extern "C" void kernel_launch(void* const* d_in, const int* in_sizes, int n_in,
                              void* d_out, int out_size, void* d_ws, size_t ws_size,
                              hipStream_t stream) {
  const float* X = (const float*)d_in[0];   // [8,4096,128,3]
  const float* J = (const float*)d_in[1];   // [8,4096,128,3,2]
  const float* A = (const float*)d_in[2];   // [256,128]
  const float* B = (const float*)d_in[3];   // [256,128]
  const float* C = (const float*)d_in[4];   // [256,128]
  const float* W = (const float*)d_in[5];   // [256,256]
  unsigned short* M3h = (unsigned short*)d_ws;          // 32768 u16
  unsigned short* M3m = M3h + 128 * 256;                // 32768 u16
  unsigned short* WMh = M3m + 128 * 256;                // 32768 u16
  unsigned short* WMm = WMh + 128 * 256;                // 32768 u16
  float* M3f = (float*)(WMm + 128 * 256);               // 32768 f32; total 384KB
  float* out = (float*)d_out;               // [8,256,3,4096]

  prep1_kernel<<<128, 256, 0, stream>>>(A, B, C, M3f, M3h, M3m);
  prep2_kernel<<<256, 256, 0, stream>>>(W, M3f, WMh, WMm);
  affine_vnrelu_mfma<<<NBLK, 512, 0, stream>>>(
      X, J, M3h, M3m, WMh, WMm, out);
}